// Round 4
// baseline (307.324 us; speedup 1.0000x reference)
//
#include <hip/hip_runtime.h>
#include <hip/hip_bf16.h>
#include <stdint.h>

#define B_ 4
#define S_ 2048
#define E_ 1024
#define BS_ (B_*S_)

using bf16x8 = __attribute__((ext_vector_type(8))) __bf16;
using f32x4  = __attribute__((ext_vector_type(4))) float;

__device__ __forceinline__ unsigned short f2bf(float f) {
  unsigned int u = __float_as_uint(f);
  u += 0x7fffu + ((u >> 16) & 1u);          // round-to-nearest-even
  return (unsigned short)(u >> 16);
}
__device__ __forceinline__ float bf2f(unsigned short h) {
  return __uint_as_float(((unsigned int)h) << 16);
}

// async global->LDS, 16B per lane; LDS dest = wave-uniform base + lane*16
__device__ __forceinline__ void gld16(const unsigned short* g, unsigned short* l) {
  __builtin_amdgcn_global_load_lds((__attribute__((address_space(1))) void*)(void*)g,
                                   (__attribute__((address_space(3))) void*)l, 16, 0, 0);
}

// ---------------- fp32 -> bf16 convert (x4 vectorized) ----------------
__global__ __launch_bounds__(256) void conv_f32_bf16(const float* __restrict__ in,
                                                     unsigned short* __restrict__ out,
                                                     int n4) {
  int i = blockIdx.x * 256 + threadIdx.x;
  if (i >= n4) return;
  const float4 v = ((const float4*)in)[i];
  ushort4 o;
  o.x = f2bf(v.x); o.y = f2bf(v.y); o.z = f2bf(v.z); o.w = f2bf(v.w);
  ((ushort4*)out)[i] = o;
}

// convert 3 weight matrices + concat 3 biases in one dispatch
__global__ __launch_bounds__(256) void prep_w(
    const float* __restrict__ Wq, const float* __restrict__ Wk, const float* __restrict__ Wv,
    const float* __restrict__ bq, const float* __restrict__ bk, const float* __restrict__ bv,
    unsigned short* __restrict__ Wb, float* __restrict__ bb) {
  const int i = blockIdx.x * 256 + threadIdx.x;
  const int n4 = E_ * E_ / 4;
  if (i < 3 * n4) {
    const int m = i / n4, j = i - m * n4;
    const float* src = (m == 0) ? Wq : (m == 1) ? Wk : Wv;
    const float4 v = ((const float4*)src)[j];
    ushort4 o;
    o.x = f2bf(v.x); o.y = f2bf(v.y); o.z = f2bf(v.z); o.w = f2bf(v.w);
    ((ushort4*)Wb)[i] = o;
  } else {
    const int j = i - 3 * n4;
    if (j < 3 * E_) bb[j] = (j < E_) ? bq[j] : (j < 2 * E_) ? bk[j - E_] : bv[j - 2 * E_];
  }
}

// ---------------- BT-GEMM with global_load_lds staging + XOR-swizzled LDS ----------------
// C[m][n] = sum_k A[m][k]*B[n][k]
// EPI 0: +bias[col] -> bf16 out
// EPI 1: *scale -> bf16 out, causal => skip blocks fully above diagonal
// EPI 2: fp32 out, causal => K-loop clipped at m0+BM (A upper part is zeros)
// Causal grids launch with blockIdx.y REVERSED (largest-K m-tiles first) so the
// longest blocks spread one-per-CU before short ones backfill.
template<int EPI>
__global__ __launch_bounds__(256, 3) void gemm_bt(
    const unsigned short* __restrict__ A, const unsigned short* __restrict__ Bm,
    float* __restrict__ Cf, unsigned short* __restrict__ Cb,
    const float* __restrict__ bias,
    int K, int lda, int ldb, int ldc,
    long sA, long sB, long sC, float scale, int causal)
{
  constexpr int BM = 128, BN = 128, BK = 64;
  __shared__ __align__(16) unsigned short As[BM * BK];
  __shared__ __align__(16) unsigned short Bs[BN * BK];
  const int bz = blockIdx.z;
  A  += sA * bz;
  Bm += sB * bz;
  const int mt = (EPI != 0) ? (gridDim.y - 1 - blockIdx.y) : blockIdx.y;
  const int m0 = mt * BM, n0 = blockIdx.x * BN;
  if (EPI == 1 && causal && n0 >= m0 + BM) return;           // fully masked block
  const int kend = (EPI == 2 && causal) ? min(K, m0 + BM) : K;
  const int t = threadIdx.x;
  const int lane = t & 63, wave = t >> 6;
  const int wr = wave >> 1, wc = wave & 1;
  const int q = lane >> 4, r = lane & 15;

  // staging: wave w handles rows [w*32, w*32+32), 4 instructions of 8 rows each
  const int srow   = lane >> 3;                 // 0..7 within an 8-row segment
  const int schunk = (lane & 7) ^ srow;         // global 16B chunk to fetch
  const long ga0 = (long)(m0 + wave * 32 + srow) * lda + schunk * 8;
  const long gb0 = (long)(n0 + wave * 32 + srow) * ldb + schunk * 8;

  f32x4 acc[4][4] = {};

  for (int k0 = 0; k0 < kend; k0 += BK) {
#pragma unroll
    for (int s = 0; s < 4; ++s) {
      gld16(A  + ga0 + (long)s * 8 * lda + k0, &As[(wave * 32 + s * 8) * 64]);
      gld16(Bm + gb0 + (long)s * 8 * ldb + k0, &Bs[(wave * 32 + s * 8) * 64]);
    }
    __syncthreads();                            // vmcnt(0) drain + barrier: tiles ready
#pragma unroll
    for (int kk = 0; kk < BK; kk += 32) {
      bf16x8 af[4], bfr[4];
      const int cq = (kk >> 3) + q;             // 16B chunk for this quad
#pragma unroll
      for (int i = 0; i < 4; ++i) {
        const int row = wr * 64 + i * 16 + r;
        af[i] = *(const bf16x8*)&As[(row * 8 + (cq ^ (r & 7))) * 8];
      }
#pragma unroll
      for (int j = 0; j < 4; ++j) {
        const int row = wc * 64 + j * 16 + r;
        bfr[j] = *(const bf16x8*)&Bs[(row * 8 + (cq ^ (r & 7))) * 8];
      }
#pragma unroll
      for (int i = 0; i < 4; ++i)
#pragma unroll
        for (int j = 0; j < 4; ++j)
          acc[i][j] = __builtin_amdgcn_mfma_f32_16x16x32_bf16(af[i], bfr[j], acc[i][j], 0, 0, 0);
    }
    __syncthreads();                            // all reads done before next staging
  }

  if (EPI == 2) Cf += sC * bz; else Cb += sC * bz;
#pragma unroll
  for (int i = 0; i < 4; ++i) {
#pragma unroll
    for (int j = 0; j < 4; ++j) {
      const int col = n0 + wc * 64 + j * 16 + r;      // C/D: col = lane&15
#pragma unroll
      for (int e = 0; e < 4; ++e) {
        const int rowg = m0 + wr * 64 + i * 16 + q * 4 + e;  // row = quad*4 + reg
        float v = acc[i][j][e];
        if (EPI == 0) {
          v += bias[col];
          Cb[(long)rowg * ldc + col] = f2bf(v);
        } else if (EPI == 1) {
          Cb[(long)rowg * ldc + col] = f2bf(v * scale);
        } else {
          Cf[(long)rowg * ldc + col] = v;
        }
      }
    }
  }
}

// ---------------- bf16 transpose per batch: V[S][E] (ld lda) -> Vt[E][S], 64x64 tiles ----------------
__global__ __launch_bounds__(256) void transpose_b(const unsigned short* __restrict__ V,
                                                   unsigned short* __restrict__ Vt, int lda) {
  __shared__ unsigned short tile[64][68];
  const int b = blockIdx.z;
  const unsigned short* Vb = V + (long)b * S_ * lda;
  unsigned short* Vtb = Vt + (long)b * S_ * E_;
  const int e0 = blockIdx.x * 64, j0 = blockIdx.y * 64;
  const int t = threadIdx.x;
#pragma unroll
  for (int i = 0; i < 4; ++i) {
    const int c = t + i * 256;                // 1024 ushort4 chunks
    const int row = c >> 4, c4 = c & 15;
    *(ushort4*)&tile[row][c4 * 4] = *(const ushort4*)&Vb[(long)(j0 + row) * lda + e0 + c4 * 4];
  }
  __syncthreads();
#pragma unroll
  for (int i = 0; i < 4; ++i) {
    const int c = t + i * 256;
    const int orow = c >> 4, c4 = c & 15;     // orow = e-offset, c4*4 = j-offset
    ushort4 o;
    o.x = tile[c4 * 4 + 0][orow];
    o.y = tile[c4 * 4 + 1][orow];
    o.z = tile[c4 * 4 + 2][orow];
    o.w = tile[c4 * 4 + 3][orow];
    *(ushort4*)&Vtb[(long)(e0 + orow) * S_ + j0 + c4 * 4] = o;
  }
}

// ---------------- causal softmax over bf16 scores, in-place, one wave per row ----------------
__global__ __launch_bounds__(256) void softmax_causal(unsigned short* __restrict__ Sc) {
  const int row = blockIdx.x * 4 + (threadIdx.x >> 6);   // 4 waves/block, 1 row/wave
  const int lane = threadIdx.x & 63;
  const int b = row >> 11, ii = row & (S_ - 1);
  unsigned short* prow = Sc + (long)b * S_ * S_ + (long)ii * S_;
  const int len = ii + 1;
  float v[32];
#pragma unroll
  for (int c = 0; c < 4; ++c) {
    const int base = (c * 64 + lane) * 8;
    if (base < len) {
      const uint4 u = *(const uint4*)&prow[base];
      const unsigned int w[4] = {u.x, u.y, u.z, u.w};
#pragma unroll
      for (int e = 0; e < 8; ++e) {
        const unsigned short h = (unsigned short)(w[e >> 1] >> ((e & 1) * 16));
        v[c * 8 + e] = (base + e < len) ? bf2f(h) : -3.0e38f;
      }
    } else {
#pragma unroll
      for (int e = 0; e < 8; ++e) v[c * 8 + e] = -3.0e38f;
    }
  }
  float mx = -3.0e38f;
#pragma unroll
  for (int i = 0; i < 32; ++i) mx = fmaxf(mx, v[i]);
#pragma unroll
  for (int o = 32; o; o >>= 1) mx = fmaxf(mx, __shfl_xor(mx, o));
  float sum = 0.f;
#pragma unroll
  for (int i = 0; i < 32; ++i) { v[i] = __expf(v[i] - mx); sum += v[i]; }
#pragma unroll
  for (int o = 32; o; o >>= 1) sum += __shfl_xor(sum, o);
  const float inv = 1.0f / sum;
#pragma unroll
  for (int c = 0; c < 4; ++c) {
    const int base = (c * 64 + lane) * 8;
    uint4 u;
    unsigned int w[4];
#pragma unroll
    for (int p = 0; p < 4; ++p) {
      const unsigned short lo = f2bf(v[c * 8 + p * 2] * inv);
      const unsigned short hi = f2bf(v[c * 8 + p * 2 + 1] * inv);
      w[p] = (unsigned int)lo | ((unsigned int)hi << 16);
    }
    u.x = w[0]; u.y = w[1]; u.z = w[2]; u.w = w[3];
    *(uint4*)&prow[base] = u;                  // rows always full-width: zeros beyond diagonal
  }
}

// ---------------- residual + LayerNorm ----------------
__global__ __launch_bounds__(256) void residual_ln(
    const float* __restrict__ attn, const float* __restrict__ x,
    const float* __restrict__ gamma, const float* __restrict__ beta,
    float* __restrict__ out) {
  __shared__ float rs[4], rs2[4];
  const long row = blockIdx.x;
  const int t = threadIdx.x;
  const int lane = t & 63, wave = t >> 6;
  const float4 a  = ((const float4*)(attn + row * E_))[t];
  const float4 xv = ((const float4*)(x + row * E_))[t];
  const float y0 = a.x + xv.x, y1 = a.y + xv.y, y2 = a.z + xv.z, y3 = a.w + xv.w;
  float s  = y0 + y1 + y2 + y3;
  float s2 = y0 * y0 + y1 * y1 + y2 * y2 + y3 * y3;
#pragma unroll
  for (int o = 32; o; o >>= 1) { s += __shfl_xor(s, o); s2 += __shfl_xor(s2, o); }
  if (lane == 0) { rs[wave] = s; rs2[wave] = s2; }
  __syncthreads();
  s  = rs[0] + rs[1] + rs[2] + rs[3];
  s2 = rs2[0] + rs2[1] + rs2[2] + rs2[3];
  const float mu  = s * (1.0f / E_);
  const float var = s2 * (1.0f / E_) - mu * mu;
  const float inv = rsqrtf(var + 1e-5f);
  const float4 g  = ((const float4*)gamma)[t];
  const float4 be = ((const float4*)beta)[t];
  float4 o;
  o.x = (y0 - mu) * inv * g.x + be.x;
  o.y = (y1 - mu) * inv * g.y + be.y;
  o.z = (y2 - mu) * inv * g.z + be.z;
  o.w = (y3 - mu) * inv * g.w + be.w;
  ((float4*)(out + row * E_))[t] = o;
}

extern "C" void kernel_launch(void* const* d_in, const int* in_sizes, int n_in,
                              void* d_out, int out_size, void* d_ws, size_t ws_size,
                              hipStream_t stream) {
  const float* x  = (const float*)d_in[0];
  // d_in[1] = causal mask (bool) — structurally known, not read
  const float* Wq = (const float*)d_in[2];
  const float* bq = (const float*)d_in[3];
  const float* Wk = (const float*)d_in[4];
  const float* bk = (const float*)d_in[5];
  const float* Wv = (const float*)d_in[6];
  const float* bv = (const float*)d_in[7];
  const float* gamma = (const float*)d_in[8];
  const float* beta  = (const float*)d_in[9];
  float* out = (float*)d_out;

  char* ws = (char*)d_ws;
  size_t off = 0;
  auto alloc = [&](size_t bytes) { char* p = ws + off; off += (bytes + 255) & ~(size_t)255; return p; };
  unsigned short* xb    = (unsigned short*)alloc((size_t)BS_ * E_ * 2);        // 16 MB
  unsigned short* Wqkvb = (unsigned short*)alloc((size_t)3 * E_ * E_ * 2);     // 6 MB
  float*          bqkv  = (float*)alloc((size_t)3 * E_ * 4);
  unsigned short* Cqkv  = (unsigned short*)alloc((size_t)BS_ * 3 * E_ * 2);    // 48 MB (Q|K|V, ld 3072)
  unsigned short* Vt    = (unsigned short*)alloc((size_t)BS_ * E_ * 2);        // 16 MB
  unsigned short* Sc    = (unsigned short*)alloc((size_t)B_ * S_ * S_ * 2);    // 32 MB bf16; P in-place
  float* attn = (float*)Cqkv;   // Q/K/V dead after scores GEMM + transpose

  // 1) converts: x, and fused weights+bias prep
  conv_f32_bf16<<<dim3(BS_ * E_ / 4 / 256), 256, 0, stream>>>(x, xb, BS_ * E_ / 4);
  prep_w<<<dim3((3 * E_ * E_ / 4 + 3 * E_ + 255) / 256), 256, 0, stream>>>(
      Wq, Wk, Wv, bq, bk, bv, Wqkvb, bqkv);

  // 2) fused QKV projection: Cqkv[8192,3072] = xb · Wqkv^T + bqkv -> bf16
  dim3 g1(3 * E_ / 128, BS_ / 128, 1);
  gemm_bt<0><<<g1, 256, 0, stream>>>(xb, Wqkvb, nullptr, Cqkv, bqkv,
                                     E_, E_, E_, 3 * E_, 0, 0, 0, 1.f, 0);

  // 3) transpose V (cols 2048..3071 of Cqkv) -> Vt[E][S] per batch
  transpose_b<<<dim3(E_ / 64, S_ / 64, B_), 256, 0, stream>>>(Cqkv + 2 * E_, Vt, 3 * E_);

  // 4) scores = Q·K^T / 32 -> bf16 (causal: skip fully-masked blocks; y reversed in-kernel)
  dim3 g2(S_ / 128, S_ / 128, B_);
  gemm_bt<1><<<g2, 256, 0, stream>>>(Cqkv, Cqkv + E_, nullptr, Sc, nullptr,
                                     E_, 3 * E_, 3 * E_, S_,
                                     (long)S_ * 3 * E_, (long)S_ * 3 * E_, (long)S_ * S_,
                                     0.03125f, 1);

  // 5) causal softmax -> P (bf16, in-place, full rows: zeros beyond diagonal)
  softmax_causal<<<dim3(BS_ / 4), 256, 0, stream>>>(Sc);

  // 6) attn = P · V  (as P · Vt^T), K-loop clipped at diagonal; longest-K blocks first
  dim3 g3(E_ / 128, S_ / 128, B_);
  gemm_bt<2><<<g3, 256, 0, stream>>>(Sc, Vt, attn, nullptr, nullptr,
                                     S_, S_, S_, E_,
                                     (long)S_ * S_, (long)S_ * E_, (long)S_ * E_, 1.f, 1);

  // 7) out = LayerNorm(attn + x) * gamma + beta
  residual_ln<<<dim3(BS_), 256, 0, stream>>>(attn, x, gamma, beta, out);
}

// Round 6
// 296.044 us; speedup vs baseline: 1.0381x; 1.0381x over previous
//
#include <hip/hip_runtime.h>
#include <hip/hip_bf16.h>
#include <stdint.h>

#define B_ 4
#define S_ 2048
#define E_ 1024
#define BS_ (B_*S_)

using bf16x8 = __attribute__((ext_vector_type(8))) __bf16;
using f32x4  = __attribute__((ext_vector_type(4))) float;

// PV split-K schedule: 24 chunks/(n,b), descending K so long chunks dispatch first.
// mt 0..7: one chunk [0, 128(mt+1)); mt 8..15: chunk0 [0,1024) -> attn, chunk1 [1024, 128(mt+1)) -> attn2
__constant__ int pv_mt[24] = {7,8,9,10,11,12,13,14,15,15,14,6,13,5,12,4,11,3,10,2,9,1,8,0};
__constant__ int pv_ck[24] = {0,0,0,0,0,0,0,0,0, 1, 1,0, 1,0, 1,0, 1,0, 1,0, 1,0, 1,0};

__device__ __forceinline__ unsigned short f2bf(float f) {
  unsigned int u = __float_as_uint(f);
  u += 0x7fffu + ((u >> 16) & 1u);          // round-to-nearest-even
  return (unsigned short)(u >> 16);
}
__device__ __forceinline__ float bf2f(unsigned short h) {
  return __uint_as_float(((unsigned int)h) << 16);
}

// async global->LDS, 16B per lane; LDS dest = wave-uniform base + lane*16
__device__ __forceinline__ void gld16(const unsigned short* g, unsigned short* l) {
  __builtin_amdgcn_global_load_lds((__attribute__((address_space(1))) void*)(void*)g,
                                   (__attribute__((address_space(3))) void*)l, 16, 0, 0);
}

// ---------------- all input prep in one launch: x->bf16, W->bf16 concat, bias concat ----------------
__global__ __launch_bounds__(256) void prep_all(
    const float* __restrict__ x,
    const float* __restrict__ Wq, const float* __restrict__ Wk, const float* __restrict__ Wv,
    const float* __restrict__ bq, const float* __restrict__ bk, const float* __restrict__ bv,
    unsigned short* __restrict__ xb, unsigned short* __restrict__ Wb, float* __restrict__ bb) {
  const int i = blockIdx.x * 256 + threadIdx.x;
  const int nx4 = BS_ * E_ / 4, nw4 = E_ * E_ / 4;
  if (i < nx4) {
    const float4 v = ((const float4*)x)[i];
    ushort4 o;
    o.x = f2bf(v.x); o.y = f2bf(v.y); o.z = f2bf(v.z); o.w = f2bf(v.w);
    ((ushort4*)xb)[i] = o;
  } else if (i < nx4 + 3 * nw4) {
    const int j = i - nx4;
    const int m = j / nw4, jj = j - m * nw4;
    const float* src = (m == 0) ? Wq : (m == 1) ? Wk : Wv;
    const float4 v = ((const float4*)src)[jj];
    ushort4 o;
    o.x = f2bf(v.x); o.y = f2bf(v.y); o.z = f2bf(v.z); o.w = f2bf(v.w);
    ((ushort4*)Wb)[j] = o;
  } else {
    const int j = i - nx4 - 3 * nw4;
    if (j < 3 * E_) bb[j] = (j < E_) ? bq[j] : (j < 2 * E_) ? bk[j - E_] : bv[j - 2 * E_];
  }
}

// ---------------- BT-GEMM with global_load_lds staging + XOR-swizzled LDS ----------------
// C[m][n] = sum_k A[m][k]*B[n][k]
// EPI 0 (QKV):   +bias[col]; cols <2048 -> bf16 Cqkv (Q|K, ld 2048); cols >=2048 -> V written TRANSPOSED to Vt
// EPI 1 (scores):*scale -> bf16; compact triangular grid (blockIdx.x = tri id, 136/batch)
// EPI 2 (PV):    fp32; split-K per pv_mt/pv_ck tables; chunk0 -> Cf(attn), chunk1 -> Cf2(attn2)
template<int EPI>
__global__ __launch_bounds__(256, 3) void gemm_bt(
    const unsigned short* __restrict__ A, const unsigned short* __restrict__ Bm,
    float* __restrict__ Cf, float* __restrict__ Cf2,
    unsigned short* __restrict__ Cb, unsigned short* __restrict__ VtOut,
    const float* __restrict__ bias,
    int K, int lda, int ldb, int ldc,
    long sA, long sB, long sC, float scale)
{
  constexpr int BM = 128, BN = 128, BK = 64;
  __shared__ __align__(16) unsigned short As[BM * BK];
  __shared__ __align__(16) unsigned short Bs[BN * BK];
  const int bz = blockIdx.z;
  A  += sA * bz;
  Bm += sB * bz;

  int mt, nt, ck = 0;
  if (EPI == 1) {                       // triangular decode: id -> (mt, nt), nt <= mt
    const int id = blockIdx.x;
    mt = (int)((sqrtf(8.f * id + 1.f) - 1.f) * 0.5f);
    while ((mt * (mt + 1)) / 2 > id) --mt;
    while (((mt + 1) * (mt + 2)) / 2 <= id) ++mt;
    nt = id - (mt * (mt + 1)) / 2;
  } else if (EPI == 2) {
    mt = pv_mt[blockIdx.y]; ck = pv_ck[blockIdx.y]; nt = blockIdx.x;
  } else {
    mt = blockIdx.y; nt = blockIdx.x;
  }
  const int m0 = mt * BM, n0 = nt * BN;
  const int k0s  = (EPI == 2 && ck) ? 1024 : 0;
  const int kend = (EPI == 2) ? (ck ? m0 + BM : min(1024, m0 + BM)) : K;

  const int t = threadIdx.x;
  const int lane = t & 63, wave = t >> 6;
  const int wr = wave >> 1, wc = wave & 1;
  const int q = lane >> 4, r = lane & 15;

  // staging: wave w handles rows [w*32, w*32+32), 4 instructions of 8 rows each
  const int srow   = lane >> 3;                 // 0..7 within an 8-row segment
  const int schunk = (lane & 7) ^ srow;         // global 16B chunk to fetch
  const long ga0 = (long)(m0 + wave * 32 + srow) * lda + schunk * 8;
  const long gb0 = (long)(n0 + wave * 32 + srow) * ldb + schunk * 8;

  f32x4 acc[4][4] = {};

  for (int k0 = k0s; k0 < kend; k0 += BK) {
#pragma unroll
    for (int s = 0; s < 4; ++s) {
      gld16(A  + ga0 + (long)s * 8 * lda + k0, &As[(wave * 32 + s * 8) * 64]);
      gld16(Bm + gb0 + (long)s * 8 * ldb + k0, &Bs[(wave * 32 + s * 8) * 64]);
    }
    __syncthreads();                            // vmcnt(0) drain + barrier: tiles ready
#pragma unroll
    for (int kk = 0; kk < BK; kk += 32) {
      bf16x8 af[4], bfr[4];
      const int cq = (kk >> 3) + q;             // 16B chunk for this quad
#pragma unroll
      for (int i = 0; i < 4; ++i) {
        const int row = wr * 64 + i * 16 + r;
        af[i] = *(const bf16x8*)&As[(row * 8 + (cq ^ (r & 7))) * 8];
      }
#pragma unroll
      for (int j = 0; j < 4; ++j) {
        const int row = wc * 64 + j * 16 + r;
        bfr[j] = *(const bf16x8*)&Bs[(row * 8 + (cq ^ (r & 7))) * 8];
      }
#pragma unroll
      for (int i = 0; i < 4; ++i)
#pragma unroll
        for (int j = 0; j < 4; ++j)
          acc[i][j] = __builtin_amdgcn_mfma_f32_16x16x32_bf16(af[i], bfr[j], acc[i][j], 0, 0, 0);
    }
    __syncthreads();                            // all reads done before next staging
  }

  if (EPI == 0) {
    if (n0 < 2 * E_) {                          // Q|K -> Cqkv (ld 2048)
#pragma unroll
      for (int i = 0; i < 4; ++i)
#pragma unroll
        for (int j = 0; j < 4; ++j) {
          const int col = n0 + wc * 64 + j * 16 + r;
          const float bia = bias[col];
#pragma unroll
          for (int e = 0; e < 4; ++e) {
            const int rowg = m0 + wr * 64 + i * 16 + q * 4 + e;
            Cb[(long)rowg * ldc + col] = f2bf(acc[i][j][e] + bia);
          }
        }
    } else {                                    // V -> Vt[b][e][s], transposed store
#pragma unroll
      for (int i = 0; i < 4; ++i) {
        const int base = m0 + wr * 64 + i * 16 + q * 4;   // 4 consecutive global rows
        const int b = base >> 11, s0 = base & (S_ - 1);
#pragma unroll
        for (int j = 0; j < 4; ++j) {
          const int col = n0 + wc * 64 + j * 16 + r;
          const int e_ = col - 2 * E_;
          const float bia = bias[col];
          ushort4 o;
          o.x = f2bf(acc[i][j][0] + bia);
          o.y = f2bf(acc[i][j][1] + bia);
          o.z = f2bf(acc[i][j][2] + bia);
          o.w = f2bf(acc[i][j][3] + bia);
          *(ushort4*)&VtOut[((long)b * E_ + e_) * S_ + s0] = o;
        }
      }
    }
  } else if (EPI == 1) {
    Cb += sC * bz;
#pragma unroll
    for (int i = 0; i < 4; ++i)
#pragma unroll
      for (int j = 0; j < 4; ++j) {
        const int col = n0 + wc * 64 + j * 16 + r;
#pragma unroll
        for (int e = 0; e < 4; ++e) {
          const int rowg = m0 + wr * 64 + i * 16 + q * 4 + e;
          Cb[(long)rowg * ldc + col] = f2bf(acc[i][j][e] * scale);
        }
      }
  } else {
    float* dst = (ck ? Cf2 : Cf) + sC * bz;
#pragma unroll
    for (int i = 0; i < 4; ++i)
#pragma unroll
      for (int j = 0; j < 4; ++j) {
        const int col = n0 + wc * 64 + j * 16 + r;
#pragma unroll
        for (int e = 0; e < 4; ++e) {
          const int rowg = m0 + wr * 64 + i * 16 + q * 4 + e;
          dst[(long)rowg * ldc + col] = acc[i][j][e];
        }
      }
  }
}

// ---------------- causal softmax over bf16 scores, in-place, one wave per row ----------------
// Writes clipped to the 128-tile boundary (all PV ever reads); zeros fill [len, wend).
__global__ __launch_bounds__(256) void softmax_causal(unsigned short* __restrict__ Sc) {
  const int row = blockIdx.x * 4 + (threadIdx.x >> 6);   // 4 waves/block, 1 row/wave
  const int lane = threadIdx.x & 63;
  const int b = row >> 11, ii = row & (S_ - 1);
  unsigned short* prow = Sc + (long)b * S_ * S_ + (long)ii * S_;
  const int len = ii + 1;
  const int wend = ((ii >> 7) + 1) << 7;        // write up to m-tile boundary only
  float v[32];
#pragma unroll
  for (int c = 0; c < 4; ++c) {
    const int base = (c * 64 + lane) * 8;
    if (base < len) {
      const uint4 u = *(const uint4*)&prow[base];
      const unsigned int w[4] = {u.x, u.y, u.z, u.w};
#pragma unroll
      for (int e = 0; e < 8; ++e) {
        const unsigned short h = (unsigned short)(w[e >> 1] >> ((e & 1) * 16));
        v[c * 8 + e] = (base + e < len) ? bf2f(h) : -3.0e38f;
      }
    } else {
#pragma unroll
      for (int e = 0; e < 8; ++e) v[c * 8 + e] = -3.0e38f;
    }
  }
  float mx = -3.0e38f;
#pragma unroll
  for (int i = 0; i < 32; ++i) mx = fmaxf(mx, v[i]);
#pragma unroll
  for (int o = 32; o; o >>= 1) mx = fmaxf(mx, __shfl_xor(mx, o));
  float sum = 0.f;
#pragma unroll
  for (int i = 0; i < 32; ++i) { v[i] = __expf(v[i] - mx); sum += v[i]; }
#pragma unroll
  for (int o = 32; o; o >>= 1) sum += __shfl_xor(sum, o);
  const float inv = 1.0f / sum;
#pragma unroll
  for (int c = 0; c < 4; ++c) {
    const int base = (c * 64 + lane) * 8;
    if (base >= wend) continue;
    uint4 u;
    unsigned int w[4];
#pragma unroll
    for (int p = 0; p < 4; ++p) {
      const unsigned short lo = f2bf(v[c * 8 + p * 2] * inv);
      const unsigned short hi = f2bf(v[c * 8 + p * 2 + 1] * inv);
      w[p] = (unsigned int)lo | ((unsigned int)hi << 16);
    }
    u.x = w[0]; u.y = w[1]; u.z = w[2]; u.w = w[3];
    *(uint4*)&prow[base] = u;
  }
}

// ---------------- residual + split-K combine + LayerNorm ----------------
__global__ __launch_bounds__(256) void residual_ln(
    const float* __restrict__ attn, const float* __restrict__ attn2,
    const float* __restrict__ x,
    const float* __restrict__ gamma, const float* __restrict__ beta,
    float* __restrict__ out) {
  __shared__ float rs[4], rs2[4];
  const long row = blockIdx.x;
  const int t = threadIdx.x;
  const int lane = t & 63, wave = t >> 6;
  const float4 a  = ((const float4*)(attn + row * E_))[t];
  const float4 xv = ((const float4*)(x + row * E_))[t];
  float4 a2 = make_float4(0.f, 0.f, 0.f, 0.f);
  if ((row & (S_ - 1)) >= 1024) a2 = ((const float4*)(attn2 + row * E_))[t];
  const float y0 = a.x + a2.x + xv.x, y1 = a.y + a2.y + xv.y;
  const float y2 = a.z + a2.z + xv.z, y3 = a.w + a2.w + xv.w;
  float s  = y0 + y1 + y2 + y3;
  float s2 = y0 * y0 + y1 * y1 + y2 * y2 + y3 * y3;
#pragma unroll
  for (int o = 32; o; o >>= 1) { s += __shfl_xor(s, o); s2 += __shfl_xor(s2, o); }
  if (lane == 0) { rs[wave] = s; rs2[wave] = s2; }
  __syncthreads();
  s  = rs[0] + rs[1] + rs[2] + rs[3];
  s2 = rs2[0] + rs2[1] + rs2[2] + rs2[3];
  const float mu  = s * (1.0f / E_);
  const float var = s2 * (1.0f / E_) - mu * mu;
  const float inv = rsqrtf(var + 1e-5f);
  const float4 g  = ((const float4*)gamma)[t];
  const float4 be = ((const float4*)beta)[t];
  float4 o;
  o.x = (y0 - mu) * inv * g.x + be.x;
  o.y = (y1 - mu) * inv * g.y + be.y;
  o.z = (y2 - mu) * inv * g.z + be.z;
  o.w = (y3 - mu) * inv * g.w + be.w;
  ((float4*)(out + row * E_))[t] = o;
}

extern "C" void kernel_launch(void* const* d_in, const int* in_sizes, int n_in,
                              void* d_out, int out_size, void* d_ws, size_t ws_size,
                              hipStream_t stream) {
  const float* x  = (const float*)d_in[0];
  // d_in[1] = causal mask (bool) — structurally known, not read
  const float* Wq = (const float*)d_in[2];
  const float* bq = (const float*)d_in[3];
  const float* Wk = (const float*)d_in[4];
  const float* bk = (const float*)d_in[5];
  const float* Wv = (const float*)d_in[6];
  const float* bv = (const float*)d_in[7];
  const float* gamma = (const float*)d_in[8];
  const float* beta  = (const float*)d_in[9];
  float* out = (float*)d_out;

  char* ws = (char*)d_ws;
  size_t off = 0;
  auto alloc = [&](size_t bytes) { char* p = ws + off; off += (bytes + 255) & ~(size_t)255; return p; };
  unsigned short* xb    = (unsigned short*)alloc((size_t)BS_ * E_ * 2);        // 16 MB
  unsigned short* Wqkvb = (unsigned short*)alloc((size_t)3 * E_ * E_ * 2);     // 6 MB
  float*          bqkv  = (float*)alloc((size_t)3 * E_ * 4);
  unsigned short* Cqkv  = (unsigned short*)alloc((size_t)BS_ * 2 * E_ * 2);    // 32 MB (Q|K, ld 2048)
  unsigned short* Vt    = (unsigned short*)alloc((size_t)BS_ * E_ * 2);        // 16 MB
  unsigned short* Sc    = (unsigned short*)alloc((size_t)B_ * S_ * S_ * 2);    // 32 MB bf16; P in-place
  float*          attn2 = (float*)alloc((size_t)BS_ * E_ * 4);                 // 32 MB split-K partial
  float* attn = (float*)Cqkv;   // 32 MB: Q/K dead after scores GEMM

  // 1) all converts in one launch
  const int nprep = BS_ * E_ / 4 + 3 * E_ * E_ / 4 + 3 * E_;
  prep_all<<<dim3((nprep + 255) / 256), 256, 0, stream>>>(x, Wq, Wk, Wv, bq, bk, bv, xb, Wqkvb, bqkv);

  // 2) fused QKV projection; Q|K -> Cqkv (ld 2048), V -> Vt transposed
  dim3 g1(3 * E_ / 128, BS_ / 128, 1);
  gemm_bt<0><<<g1, 256, 0, stream>>>(xb, Wqkvb, nullptr, nullptr, Cqkv, Vt, bqkv,
                                     E_, E_, E_, 2 * E_, 0, 0, 0, 1.f);

  // 3) scores = Q·K^T / 32 -> bf16, compact triangular grid (136 blocks/batch)
  dim3 g2(136, 1, B_);
  gemm_bt<1><<<g2, 256, 0, stream>>>(Cqkv, Cqkv + E_, nullptr, nullptr, Sc, nullptr, nullptr,
                                     E_, 2 * E_, 2 * E_, S_,
                                     (long)S_ * 2 * E_, (long)S_ * 2 * E_, (long)S_ * S_, 0.03125f);

  // 4) causal softmax -> P (bf16 in-place, writes clipped to 128-tile boundary)
  softmax_causal<<<dim3(BS_ / 4), 256, 0, stream>>>(Sc);

  // 5) attn = P · V (as P · Vt^T), split-K balanced: 8 x 24 x 4 = 768 blocks, max K=1024
  dim3 g3(E_ / 128, 24, B_);
  gemm_bt<2><<<g3, 256, 0, stream>>>(Sc, Vt, attn, attn2, nullptr, nullptr, nullptr,
                                     S_, S_, S_, E_,
                                     (long)S_ * S_, (long)S_ * E_, (long)S_ * E_, 1.f);

  // 6) out = LayerNorm(attn [+ attn2] + x) * gamma + beta
  residual_ln<<<dim3(BS_), 256, 0, stream>>>(attn, attn2, x, gamma, beta, out);
}

// Round 7
// 277.068 us; speedup vs baseline: 1.1092x; 1.0685x over previous
//
#include <hip/hip_runtime.h>
#include <hip/hip_bf16.h>
#include <stdint.h>

#define B_ 4
#define S_ 2048
#define E_ 1024
#define BS_ (B_*S_)

using bf16x8 = __attribute__((ext_vector_type(8))) __bf16;
using f32x4  = __attribute__((ext_vector_type(4))) float;

// PV split-K schedule: 24 chunks/(n,b), descending K so long chunks dispatch first.
// mt 0..7: one chunk [0, 128(mt+1)); mt 8..15: chunk0 [0,1024) -> attn, chunk1 [1024, 128(mt+1)) -> attn2
__constant__ int pv_mt[24] = {7,8,9,10,11,12,13,14,15,15,14,6,13,5,12,4,11,3,10,2,9,1,8,0};
__constant__ int pv_ck[24] = {0,0,0,0,0,0,0,0,0, 1, 1,0, 1,0, 1,0, 1,0, 1,0, 1,0, 1,0};

__device__ __forceinline__ unsigned short f2bf(float f) {
  unsigned int u = __float_as_uint(f);
  u += 0x7fffu + ((u >> 16) & 1u);          // round-to-nearest-even
  return (unsigned short)(u >> 16);
}
__device__ __forceinline__ float bf2f(unsigned short h) {
  return __uint_as_float(((unsigned int)h) << 16);
}

// async global->LDS, 16B per lane; LDS dest = wave-uniform base + lane*16
__device__ __forceinline__ void gld16(const unsigned short* g, unsigned short* l) {
  __builtin_amdgcn_global_load_lds((__attribute__((address_space(1))) void*)(void*)g,
                                   (__attribute__((address_space(3))) void*)l, 16, 0, 0);
}

// ---------------- all input prep in one launch: x->bf16, W->bf16 concat, bias concat ----------------
__global__ __launch_bounds__(256) void prep_all(
    const float* __restrict__ x,
    const float* __restrict__ Wq, const float* __restrict__ Wk, const float* __restrict__ Wv,
    const float* __restrict__ bq, const float* __restrict__ bk, const float* __restrict__ bv,
    unsigned short* __restrict__ xb, unsigned short* __restrict__ Wb, float* __restrict__ bb) {
  const int i = blockIdx.x * 256 + threadIdx.x;
  const int nx4 = BS_ * E_ / 4, nw4 = E_ * E_ / 4;
  if (i < nx4) {
    const float4 v = ((const float4*)x)[i];
    ushort4 o;
    o.x = f2bf(v.x); o.y = f2bf(v.y); o.z = f2bf(v.z); o.w = f2bf(v.w);
    ((ushort4*)xb)[i] = o;
  } else if (i < nx4 + 3 * nw4) {
    const int j = i - nx4;
    const int m = j / nw4, jj = j - m * nw4;
    const float* src = (m == 0) ? Wq : (m == 1) ? Wk : Wv;
    const float4 v = ((const float4*)src)[jj];
    ushort4 o;
    o.x = f2bf(v.x); o.y = f2bf(v.y); o.z = f2bf(v.z); o.w = f2bf(v.w);
    ((ushort4*)Wb)[j] = o;
  } else {
    const int j = i - nx4 - 3 * nw4;
    if (j < 3 * E_) bb[j] = (j < E_) ? bq[j] : (j < 2 * E_) ? bk[j - E_] : bv[j - 2 * E_];
  }
}

// ---------------- BT-GEMM with global_load_lds staging + XOR-swizzled LDS ----------------
// C[m][n] = sum_k A[m][k]*B[n][k]
// EPI 0 (QKV):   +bias; cols <2048 -> bf16 Cqkv; cols >=2048 -> V stored transposed to Vt via
//                per-wave LDS scratch (coalesced 16B-segment stores, not 8B scatter)
// EPI 1 (scores):*scale -> bf16; 1D grid 544; sigma-permuted so each XCD (id%8) gets a
//                contiguous run of locality-ordered 4x4 super-tiles (Q/K panels stay in its L2)
// EPI 2 (PV):    fp32; split-K per pv_mt/pv_ck tables; chunk0 -> Cf(attn), chunk1 -> Cf2(attn2)
template<int EPI>
__global__ __launch_bounds__(256, 3) void gemm_bt(
    const unsigned short* __restrict__ A, const unsigned short* __restrict__ Bm,
    float* __restrict__ Cf, float* __restrict__ Cf2,
    unsigned short* __restrict__ Cb, unsigned short* __restrict__ VtOut,
    const float* __restrict__ bias,
    int K, int lda, int ldb, int ldc,
    long sA, long sB, long sC, float scale)
{
  constexpr int BM = 128, BN = 128, BK = 64;
  __shared__ __align__(16) unsigned short As[BM * BK];
  __shared__ __align__(16) unsigned short Bs[BN * BK];

  int mt, nt, ck = 0, bz;
  if (EPI == 1) {
    // sigma: XCD c = id%8 processes contiguous locality-ordered segment [68c, 68c+68)
    const int sig = (blockIdx.x & 7) * 68 + (blockIdx.x >> 3);
    bz = sig / 136;
    const int rem = sig - bz * 136;
    const int M = (rem >= 78) ? 3 : (rem >= 36) ? 2 : (rem >= 10) ? 1 : 0;
    const int cumM = (M == 3) ? 78 : (M == 2) ? 36 : (M == 1) ? 10 : 0;
    const int inner = rem - cumM;
    if (inner < 16 * M) {               // full 4x4 super (N < M)
      const int N = inner >> 4, t2 = inner & 15;
      mt = 4 * M + (t2 >> 2); nt = 4 * N + (t2 & 3);
    } else {                            // diagonal tri super (N == M), 10 tiles
      const int t2 = inner - 16 * M;
      const int ml = (t2 >= 6) ? 3 : (t2 >= 3) ? 2 : (t2 >= 1) ? 1 : 0;
      const int nl = t2 - (ml * (ml + 1)) / 2;
      mt = 4 * M + ml; nt = 4 * M + nl;
    }
  } else if (EPI == 2) {
    mt = pv_mt[blockIdx.y]; ck = pv_ck[blockIdx.y]; nt = blockIdx.x; bz = blockIdx.z;
  } else {
    mt = blockIdx.y; nt = blockIdx.x; bz = blockIdx.z;
  }
  A  += sA * bz;
  Bm += sB * bz;
  const int m0 = mt * BM, n0 = nt * BN;
  const int k0s  = (EPI == 2 && ck) ? 1024 : 0;
  const int kend = (EPI == 2) ? (ck ? m0 + BM : min(1024, m0 + BM)) : K;

  const int t = threadIdx.x;
  const int lane = t & 63, wave = t >> 6;
  const int wr = wave >> 1, wc = wave & 1;
  const int q = lane >> 4, r = lane & 15;

  // staging: wave w handles rows [w*32, w*32+32), 4 instructions of 8 rows each
  const int srow   = lane >> 3;                 // 0..7 within an 8-row segment
  const int schunk = (lane & 7) ^ srow;         // global 16B chunk to fetch
  const long ga0 = (long)(m0 + wave * 32 + srow) * lda + schunk * 8;
  const long gb0 = (long)(n0 + wave * 32 + srow) * ldb + schunk * 8;

  f32x4 acc[4][4] = {};

  for (int k0 = k0s; k0 < kend; k0 += BK) {
#pragma unroll
    for (int s = 0; s < 4; ++s) {
      gld16(A  + ga0 + (long)s * 8 * lda + k0, &As[(wave * 32 + s * 8) * 64]);
      gld16(Bm + gb0 + (long)s * 8 * ldb + k0, &Bs[(wave * 32 + s * 8) * 64]);
    }
    __syncthreads();                            // vmcnt(0) drain + barrier: tiles ready
#pragma unroll
    for (int kk = 0; kk < BK; kk += 32) {
      bf16x8 af[4], bfr[4];
      const int cq = (kk >> 3) + q;             // 16B chunk for this quad
#pragma unroll
      for (int i = 0; i < 4; ++i) {
        const int row = wr * 64 + i * 16 + r;
        af[i] = *(const bf16x8*)&As[(row * 8 + (cq ^ (r & 7))) * 8];
      }
#pragma unroll
      for (int j = 0; j < 4; ++j) {
        const int row = wc * 64 + j * 16 + r;
        bfr[j] = *(const bf16x8*)&Bs[(row * 8 + (cq ^ (r & 7))) * 8];
      }
#pragma unroll
      for (int i = 0; i < 4; ++i)
#pragma unroll
        for (int j = 0; j < 4; ++j)
          acc[i][j] = __builtin_amdgcn_mfma_f32_16x16x32_bf16(af[i], bfr[j], acc[i][j], 0, 0, 0);
    }
    __syncthreads();                            // all reads done before next staging
  }

  if (EPI == 0) {
    if (n0 < 2 * E_) {                          // Q|K -> Cqkv (ld 2048)
#pragma unroll
      for (int i = 0; i < 4; ++i)
#pragma unroll
        for (int j = 0; j < 4; ++j) {
          const int col = n0 + wc * 64 + j * 16 + r;
          const float bia = bias[col];
#pragma unroll
          for (int e = 0; e < 4; ++e) {
            const int rowg = m0 + wr * 64 + i * 16 + q * 4 + e;
            Cb[(long)rowg * ldc + col] = f2bf(acc[i][j][e] + bia);
          }
        }
    } else {
      // V -> Vt[b][e][s]: per-wave LDS scratch transpose, then coalesced 16B stores.
      // scratch layout: 16 e-rows x stride 72; s-chunk c stored at slot c^(e&7).
      unsigned short* scr = As + wave * 2048;   // 4 KB private scratch (K-loop done; per-wave reuse)
      const int bb = m0 >> 11;
      const int sbase = (m0 & (S_ - 1)) + wr * 64;
      const float bia = bias[n0 + wc * 64 + /*j*16*/ 0 + r];  // per-j below; placeholder unused
      (void)bia;
#pragma unroll
      for (int j = 0; j < 4; ++j) {
        const int e_base = n0 - 2 * E_ + wc * 64 + j * 16;
        const float bj = bias[n0 + wc * 64 + j * 16 + r];
        // write phase: lane (q,r) owns e-row r, s-positions i*16+q*4..+3
#pragma unroll
        for (int i = 0; i < 4; ++i) {
          const int c = 2 * i + (q >> 1);       // s-chunk (8 elems)
          const int slot = c ^ (r & 7);
          ushort4 o;
          o.x = f2bf(acc[i][j][0] + bj);
          o.y = f2bf(acc[i][j][1] + bj);
          o.z = f2bf(acc[i][j][2] + bj);
          o.w = f2bf(acc[i][j][3] + bj);
          *(ushort4*)&scr[r * 72 + slot * 8 + (q & 1) * 4] = o;
        }
        // read phase: lane -> (e-row er, slot w); slot w holds s-chunk w^er
#pragma unroll
        for (int it = 0; it < 2; ++it) {
          const int er = it * 8 + (lane >> 3);
          const int w = lane & 7;
          const bf16x8 vv = *(const bf16x8*)&scr[er * 72 + w * 8];
          const int so = (w ^ (er & 7)) * 8;
          *(bf16x8*)&VtOut[((long)bb * E_ + e_base + er) * S_ + sbase + so] = vv;
        }
      }
    }
  } else if (EPI == 1) {
    Cb += sC * bz;
#pragma unroll
    for (int i = 0; i < 4; ++i)
#pragma unroll
      for (int j = 0; j < 4; ++j) {
        const int col = n0 + wc * 64 + j * 16 + r;
#pragma unroll
        for (int e = 0; e < 4; ++e) {
          const int rowg = m0 + wr * 64 + i * 16 + q * 4 + e;
          Cb[(long)rowg * ldc + col] = f2bf(acc[i][j][e] * scale);
        }
      }
  } else {
    float* dst = (ck ? Cf2 : Cf) + sC * bz;
#pragma unroll
    for (int i = 0; i < 4; ++i)
#pragma unroll
      for (int j = 0; j < 4; ++j) {
        const int col = n0 + wc * 64 + j * 16 + r;
#pragma unroll
        for (int e = 0; e < 4; ++e) {
          const int rowg = m0 + wr * 64 + i * 16 + q * 4 + e;
          dst[(long)rowg * ldc + col] = acc[i][j][e];
        }
      }
  }
}

// ---------------- causal softmax over bf16 scores, in-place, one wave per row ----------------
// Writes clipped to the 128-tile boundary (all PV ever reads); zeros fill [len, wend).
__global__ __launch_bounds__(256) void softmax_causal(unsigned short* __restrict__ Sc) {
  const int row = blockIdx.x * 4 + (threadIdx.x >> 6);   // 4 waves/block, 1 row/wave
  const int lane = threadIdx.x & 63;
  const int b = row >> 11, ii = row & (S_ - 1);
  unsigned short* prow = Sc + (long)b * S_ * S_ + (long)ii * S_;
  const int len = ii + 1;
  const int wend = ((ii >> 7) + 1) << 7;        // write up to m-tile boundary only
  float v[32];
#pragma unroll
  for (int c = 0; c < 4; ++c) {
    const int base = (c * 64 + lane) * 8;
    if (base < len) {
      const uint4 u = *(const uint4*)&prow[base];
      const unsigned int w[4] = {u.x, u.y, u.z, u.w};
#pragma unroll
      for (int e = 0; e < 8; ++e) {
        const unsigned short h = (unsigned short)(w[e >> 1] >> ((e & 1) * 16));
        v[c * 8 + e] = (base + e < len) ? bf2f(h) : -3.0e38f;
      }
    } else {
#pragma unroll
      for (int e = 0; e < 8; ++e) v[c * 8 + e] = -3.0e38f;
    }
  }
  float mx = -3.0e38f;
#pragma unroll
  for (int i = 0; i < 32; ++i) mx = fmaxf(mx, v[i]);
#pragma unroll
  for (int o = 32; o; o >>= 1) mx = fmaxf(mx, __shfl_xor(mx, o));
  float sum = 0.f;
#pragma unroll
  for (int i = 0; i < 32; ++i) { v[i] = __expf(v[i] - mx); sum += v[i]; }
#pragma unroll
  for (int o = 32; o; o >>= 1) sum += __shfl_xor(sum, o);
  const float inv = 1.0f / sum;
#pragma unroll
  for (int c = 0; c < 4; ++c) {
    const int base = (c * 64 + lane) * 8;
    if (base >= wend) continue;
    uint4 u;
    unsigned int w[4];
#pragma unroll
    for (int p = 0; p < 4; ++p) {
      const unsigned short lo = f2bf(v[c * 8 + p * 2] * inv);
      const unsigned short hi = f2bf(v[c * 8 + p * 2 + 1] * inv);
      w[p] = (unsigned int)lo | ((unsigned int)hi << 16);
    }
    u.x = w[0]; u.y = w[1]; u.z = w[2]; u.w = w[3];
    *(uint4*)&prow[base] = u;
  }
}

// ---------------- residual + split-K combine + LayerNorm ----------------
__global__ __launch_bounds__(256) void residual_ln(
    const float* __restrict__ attn, const float* __restrict__ attn2,
    const float* __restrict__ x,
    const float* __restrict__ gamma, const float* __restrict__ beta,
    float* __restrict__ out) {
  __shared__ float rs[4], rs2[4];
  const long row = blockIdx.x;
  const int t = threadIdx.x;
  const int lane = t & 63, wave = t >> 6;
  const float4 a  = ((const float4*)(attn + row * E_))[t];
  const float4 xv = ((const float4*)(x + row * E_))[t];
  float4 a2 = make_float4(0.f, 0.f, 0.f, 0.f);
  if ((row & (S_ - 1)) >= 1024) a2 = ((const float4*)(attn2 + row * E_))[t];
  const float y0 = a.x + a2.x + xv.x, y1 = a.y + a2.y + xv.y;
  const float y2 = a.z + a2.z + xv.z, y3 = a.w + a2.w + xv.w;
  float s  = y0 + y1 + y2 + y3;
  float s2 = y0 * y0 + y1 * y1 + y2 * y2 + y3 * y3;
#pragma unroll
  for (int o = 32; o; o >>= 1) { s += __shfl_xor(s, o); s2 += __shfl_xor(s2, o); }
  if (lane == 0) { rs[wave] = s; rs2[wave] = s2; }
  __syncthreads();
  s  = rs[0] + rs[1] + rs[2] + rs[3];
  s2 = rs2[0] + rs2[1] + rs2[2] + rs2[3];
  const float mu  = s * (1.0f / E_);
  const float var = s2 * (1.0f / E_) - mu * mu;
  const float inv = rsqrtf(var + 1e-5f);
  const float4 g  = ((const float4*)gamma)[t];
  const float4 be = ((const float4*)beta)[t];
  float4 o;
  o.x = (y0 - mu) * inv * g.x + be.x;
  o.y = (y1 - mu) * inv * g.y + be.y;
  o.z = (y2 - mu) * inv * g.z + be.z;
  o.w = (y3 - mu) * inv * g.w + be.w;
  ((float4*)(out + row * E_))[t] = o;
}

extern "C" void kernel_launch(void* const* d_in, const int* in_sizes, int n_in,
                              void* d_out, int out_size, void* d_ws, size_t ws_size,
                              hipStream_t stream) {
  const float* x  = (const float*)d_in[0];
  // d_in[1] = causal mask (bool) — structurally known, not read
  const float* Wq = (const float*)d_in[2];
  const float* bq = (const float*)d_in[3];
  const float* Wk = (const float*)d_in[4];
  const float* bk = (const float*)d_in[5];
  const float* Wv = (const float*)d_in[6];
  const float* bv = (const float*)d_in[7];
  const float* gamma = (const float*)d_in[8];
  const float* beta  = (const float*)d_in[9];
  float* out = (float*)d_out;

  char* ws = (char*)d_ws;
  size_t off = 0;
  auto alloc = [&](size_t bytes) { char* p = ws + off; off += (bytes + 255) & ~(size_t)255; return p; };
  unsigned short* xb    = (unsigned short*)alloc((size_t)BS_ * E_ * 2);        // 16 MB
  unsigned short* Wqkvb = (unsigned short*)alloc((size_t)3 * E_ * E_ * 2);     // 6 MB
  float*          bqkv  = (float*)alloc((size_t)3 * E_ * 4);
  unsigned short* Cqkv  = (unsigned short*)alloc((size_t)BS_ * 2 * E_ * 2);    // 32 MB (Q|K, ld 2048)
  unsigned short* Vt    = (unsigned short*)alloc((size_t)BS_ * E_ * 2);        // 16 MB
  unsigned short* Sc    = (unsigned short*)alloc((size_t)B_ * S_ * S_ * 2);    // 32 MB bf16; P in-place
  float*          attn2 = (float*)alloc((size_t)BS_ * E_ * 4);                 // 32 MB split-K partial
  float* attn = (float*)Cqkv;   // 32 MB: Q/K dead after scores GEMM

  // 1) all converts in one launch
  const int nprep = BS_ * E_ / 4 + 3 * E_ * E_ / 4 + 3 * E_;
  prep_all<<<dim3((nprep + 255) / 256), 256, 0, stream>>>(x, Wq, Wk, Wv, bq, bk, bv, xb, Wqkvb, bqkv);

  // 2) fused QKV projection; Q|K -> Cqkv (ld 2048), V -> Vt transposed (LDS-coalesced)
  dim3 g1(3 * E_ / 128, BS_ / 128, 1);
  gemm_bt<0><<<g1, 256, 0, stream>>>(xb, Wqkvb, nullptr, nullptr, Cqkv, Vt, bqkv,
                                     E_, E_, E_, 2 * E_, 0, 0, 0, 1.f);

  // 3) scores = Q·K^T / 32 -> bf16, XCD-banded super-tile 1D grid (544 blocks)
  gemm_bt<1><<<dim3(544), 256, 0, stream>>>(Cqkv, Cqkv + E_, nullptr, nullptr, Sc, nullptr, nullptr,
                                            E_, 2 * E_, 2 * E_, S_,
                                            (long)S_ * 2 * E_, (long)S_ * 2 * E_, (long)S_ * S_,
                                            0.03125f);

  // 4) causal softmax -> P (bf16 in-place, writes clipped to 128-tile boundary)
  softmax_causal<<<dim3(BS_ / 4), 256, 0, stream>>>(Sc);

  // 5) attn = P · V (as P · Vt^T), split-K balanced: 8 x 24 x 4 = 768 blocks, max K=1024
  dim3 g3(E_ / 128, 24, B_);
  gemm_bt<2><<<g3, 256, 0, stream>>>(Sc, Vt, attn, attn2, nullptr, nullptr, nullptr,
                                     S_, S_, S_, E_,
                                     (long)S_ * S_, (long)S_ * E_, (long)S_ * E_, 1.f);

  // 6) out = LayerNorm(attn [+ attn2] + x) * gamma + beta
  residual_ln<<<dim3(BS_), 256, 0, stream>>>(attn, attn2, x, gamma, beta, out);
}

// Round 8
// 273.513 us; speedup vs baseline: 1.1236x; 1.0130x over previous
//
#include <hip/hip_runtime.h>
#include <hip/hip_bf16.h>
#include <stdint.h>

#define B_ 4
#define S_ 2048
#define E_ 1024
#define BS_ (B_*S_)

using bf16x8 = __attribute__((ext_vector_type(8))) __bf16;
using f32x4  = __attribute__((ext_vector_type(4))) float;

// PV split-K schedule: 24 chunks/(n,b), descending K so long chunks dispatch first.
// mt 0..7: one chunk [0, 128(mt+1)); mt 8..15: chunk0 [0,1024) -> attn, chunk1 [1024, 128(mt+1)) -> attn2
__constant__ int pv_mt[24] = {7,8,9,10,11,12,13,14,15,15,14,6,13,5,12,4,11,3,10,2,9,1,8,0};
__constant__ int pv_ck[24] = {0,0,0,0,0,0,0,0,0, 1, 1,0, 1,0, 1,0, 1,0, 1,0, 1,0, 1,0};

__device__ __forceinline__ unsigned short f2bf(float f) {
  unsigned int u = __float_as_uint(f);
  u += 0x7fffu + ((u >> 16) & 1u);          // round-to-nearest-even
  return (unsigned short)(u >> 16);
}
__device__ __forceinline__ float bf2f(unsigned short h) {
  return __uint_as_float(((unsigned int)h) << 16);
}

// async global->LDS, 16B per lane; LDS dest = wave-uniform base + lane*16
__device__ __forceinline__ void gld16(const unsigned short* g, unsigned short* l) {
  __builtin_amdgcn_global_load_lds((__attribute__((address_space(1))) void*)(void*)g,
                                   (__attribute__((address_space(3))) void*)l, 16, 0, 0);
}

// ---------------- prep: x->bf16, W->bf16 concat, bias concat, zero l ----------------
__global__ __launch_bounds__(256) void prep_all(
    const float* __restrict__ x,
    const float* __restrict__ Wq, const float* __restrict__ Wk, const float* __restrict__ Wv,
    const float* __restrict__ bq, const float* __restrict__ bk, const float* __restrict__ bv,
    unsigned short* __restrict__ xb, unsigned short* __restrict__ Wb, float* __restrict__ bb,
    float* __restrict__ lz) {
  const int i = blockIdx.x * 256 + threadIdx.x;
  const int nx4 = BS_ * E_ / 4, nw4 = E_ * E_ / 4;
  if (i < nx4) {
    const float4 v = ((const float4*)x)[i];
    ushort4 o;
    o.x = f2bf(v.x); o.y = f2bf(v.y); o.z = f2bf(v.z); o.w = f2bf(v.w);
    ((ushort4*)xb)[i] = o;
  } else if (i < nx4 + 3 * nw4) {
    const int j = i - nx4;
    const int m = j / nw4, jj = j - m * nw4;
    const float* src = (m == 0) ? Wq : (m == 1) ? Wk : Wv;
    const float4 v = ((const float4*)src)[jj];
    ushort4 o;
    o.x = f2bf(v.x); o.y = f2bf(v.y); o.z = f2bf(v.z); o.w = f2bf(v.w);
    ((ushort4*)Wb)[j] = o;
  } else {
    const int j = i - nx4 - 3 * nw4;
    if (j < 3 * E_) bb[j] = (j < E_) ? bq[j] : (j < 2 * E_) ? bk[j - E_] : bv[j - 2 * E_];
    else { const int k = j - 3 * E_; if (k < BS_) lz[k] = 0.f; }
  }
}

// ---------------- BT-GEMM with global_load_lds staging + XOR-swizzled LDS ----------------
// C[m][n] = sum_k A[m][k]*B[n][k]
// EPI 0 (QKV):   +bias; cols <2048 -> bf16 Cqkv; cols >=2048 -> V stored transposed to Vt via
//                per-wave LDS scratch (coalesced 16B-segment stores)
// EPI 1 (scores):mask+exp(s*scale) -> bf16 P_unnorm; per-row atomicAdd rowsum into Cf(=l).
//                XCD-banded super-tile 1D grid (544 blocks)
// EPI 2 (PV):    divide by l (Cf), write bf16; split-K: chunk0 -> Cb(attn), chunk1 -> VtOut(attn2)
template<int EPI>
__global__ __launch_bounds__(256, 3) void gemm_bt(
    const unsigned short* __restrict__ A, const unsigned short* __restrict__ Bm,
    float* __restrict__ Cf,
    unsigned short* __restrict__ Cb, unsigned short* __restrict__ VtOut,
    const float* __restrict__ bias,
    int K, int lda, int ldb, int ldc,
    long sA, long sB, long sC, float scale)
{
  constexpr int BM = 128, BN = 128, BK = 64;
  __shared__ __align__(16) unsigned short As[BM * BK];
  __shared__ __align__(16) unsigned short Bs[BN * BK];

  int mt, nt, ck = 0, bz;
  if (EPI == 1) {
    // sigma: XCD c = id%8 processes contiguous locality-ordered segment [68c, 68c+68)
    const int sig = (blockIdx.x & 7) * 68 + (blockIdx.x >> 3);
    bz = sig / 136;
    const int rem = sig - bz * 136;
    const int M = (rem >= 78) ? 3 : (rem >= 36) ? 2 : (rem >= 10) ? 1 : 0;
    const int cumM = (M == 3) ? 78 : (M == 2) ? 36 : (M == 1) ? 10 : 0;
    const int inner = rem - cumM;
    if (inner < 16 * M) {               // full 4x4 super (N < M)
      const int N = inner >> 4, t2 = inner & 15;
      mt = 4 * M + (t2 >> 2); nt = 4 * N + (t2 & 3);
    } else {                            // diagonal tri super (N == M), 10 tiles
      const int t2 = inner - 16 * M;
      const int ml = (t2 >= 6) ? 3 : (t2 >= 3) ? 2 : (t2 >= 1) ? 1 : 0;
      const int nl = t2 - (ml * (ml + 1)) / 2;
      mt = 4 * M + ml; nt = 4 * M + nl;
    }
  } else if (EPI == 2) {
    mt = pv_mt[blockIdx.y]; ck = pv_ck[blockIdx.y]; nt = blockIdx.x; bz = blockIdx.z;
  } else {
    mt = blockIdx.y; nt = blockIdx.x; bz = blockIdx.z;
  }
  A  += sA * bz;
  Bm += sB * bz;
  const int m0 = mt * BM, n0 = nt * BN;
  const int k0s  = (EPI == 2 && ck) ? 1024 : 0;
  const int kend = (EPI == 2) ? (ck ? m0 + BM : min(1024, m0 + BM)) : K;

  const int t = threadIdx.x;
  const int lane = t & 63, wave = t >> 6;
  const int wr = wave >> 1, wc = wave & 1;
  const int q = lane >> 4, r = lane & 15;

  // staging: wave w handles rows [w*32, w*32+32), 4 instructions of 8 rows each
  const int srow   = lane >> 3;                 // 0..7 within an 8-row segment
  const int schunk = (lane & 7) ^ srow;         // global 16B chunk to fetch
  const long ga0 = (long)(m0 + wave * 32 + srow) * lda + schunk * 8;
  const long gb0 = (long)(n0 + wave * 32 + srow) * ldb + schunk * 8;

  f32x4 acc[4][4] = {};

  for (int k0 = k0s; k0 < kend; k0 += BK) {
#pragma unroll
    for (int s = 0; s < 4; ++s) {
      gld16(A  + ga0 + (long)s * 8 * lda + k0, &As[(wave * 32 + s * 8) * 64]);
      gld16(Bm + gb0 + (long)s * 8 * ldb + k0, &Bs[(wave * 32 + s * 8) * 64]);
    }
    __syncthreads();                            // vmcnt(0) drain + barrier: tiles ready
#pragma unroll
    for (int kk = 0; kk < BK; kk += 32) {
      bf16x8 af[4], bfr[4];
      const int cq = (kk >> 3) + q;             // 16B chunk for this quad
#pragma unroll
      for (int i = 0; i < 4; ++i) {
        const int row = wr * 64 + i * 16 + r;
        af[i] = *(const bf16x8*)&As[(row * 8 + (cq ^ (r & 7))) * 8];
      }
#pragma unroll
      for (int j = 0; j < 4; ++j) {
        const int row = wc * 64 + j * 16 + r;
        bfr[j] = *(const bf16x8*)&Bs[(row * 8 + (cq ^ (r & 7))) * 8];
      }
#pragma unroll
      for (int i = 0; i < 4; ++i)
#pragma unroll
        for (int j = 0; j < 4; ++j)
          acc[i][j] = __builtin_amdgcn_mfma_f32_16x16x32_bf16(af[i], bfr[j], acc[i][j], 0, 0, 0);
    }
    __syncthreads();                            // all reads done before next staging
  }

  if (EPI == 0) {
    if (n0 < 2 * E_) {                          // Q|K -> Cqkv (ld 2048)
#pragma unroll
      for (int i = 0; i < 4; ++i)
#pragma unroll
        for (int j = 0; j < 4; ++j) {
          const int col = n0 + wc * 64 + j * 16 + r;
          const float bia = bias[col];
#pragma unroll
          for (int e = 0; e < 4; ++e) {
            const int rowg = m0 + wr * 64 + i * 16 + q * 4 + e;
            Cb[(long)rowg * ldc + col] = f2bf(acc[i][j][e] + bia);
          }
        }
    } else {
      // V -> Vt[b][e][s]: per-wave LDS scratch transpose, then coalesced 16B stores.
      unsigned short* scr = As + wave * 2048;   // 4 KB private scratch (K-loop done)
      const int bb = m0 >> 11;
      const int sbase = (m0 & (S_ - 1)) + wr * 64;
#pragma unroll
      for (int j = 0; j < 4; ++j) {
        const int e_base = n0 - 2 * E_ + wc * 64 + j * 16;
        const float bj = bias[n0 + wc * 64 + j * 16 + r];
#pragma unroll
        for (int i = 0; i < 4; ++i) {
          const int c = 2 * i + (q >> 1);       // s-chunk (8 elems)
          const int slot = c ^ (r & 7);
          ushort4 o;
          o.x = f2bf(acc[i][j][0] + bj);
          o.y = f2bf(acc[i][j][1] + bj);
          o.z = f2bf(acc[i][j][2] + bj);
          o.w = f2bf(acc[i][j][3] + bj);
          *(ushort4*)&scr[r * 72 + slot * 8 + (q & 1) * 4] = o;
        }
#pragma unroll
        for (int it = 0; it < 2; ++it) {
          const int er = it * 8 + (lane >> 3);
          const int w = lane & 7;
          const bf16x8 vv = *(const bf16x8*)&scr[er * 72 + w * 8];
          const int so = (w ^ (er & 7)) * 8;
          *(bf16x8*)&VtOut[((long)bb * E_ + e_base + er) * S_ + sbase + so] = vv;
        }
      }
    }
  } else if (EPI == 1) {
    // mask + exp + write P_unnorm (bf16) + per-row atomic rowsum
    Cb += sC * bz;
    float* lv = Cf + (long)bz * S_;
#pragma unroll
    for (int i = 0; i < 4; ++i) {
      float rs[4] = {0.f, 0.f, 0.f, 0.f};
#pragma unroll
      for (int j = 0; j < 4; ++j) {
        const int col = n0 + wc * 64 + j * 16 + r;
#pragma unroll
        for (int e = 0; e < 4; ++e) {
          const int rowg = m0 + wr * 64 + i * 16 + q * 4 + e;
          float p = 0.f;
          if (col <= rowg) p = __expf(fminf(acc[i][j][e] * scale, 60.f));
          Cb[(long)rowg * ldc + col] = f2bf(p);
          rs[e] += p;
        }
      }
#pragma unroll
      for (int e = 0; e < 4; ++e) {
        float s = rs[e];
        s += __shfl_xor(s, 1); s += __shfl_xor(s, 2);
        s += __shfl_xor(s, 4); s += __shfl_xor(s, 8);   // reduce across the 16 r-lanes
        if (r == 0) atomicAdd(&lv[m0 + wr * 64 + i * 16 + q * 4 + e], s);
      }
    }
  } else {
    // PV: normalize by rowsum, write bf16
    const float* lv = Cf + (long)bz * S_;
    unsigned short* dst = (ck ? VtOut : Cb) + sC * bz;
#pragma unroll
    for (int i = 0; i < 4; ++i) {
      const int rb = m0 + wr * 64 + i * 16 + q * 4;
      const float4 l4 = *(const float4*)&lv[rb];
      const float r0 = 1.f / l4.x, r1 = 1.f / l4.y, r2 = 1.f / l4.z, r3 = 1.f / l4.w;
#pragma unroll
      for (int j = 0; j < 4; ++j) {
        const int col = n0 + wc * 64 + j * 16 + r;
        dst[(long)(rb + 0) * ldc + col] = f2bf(acc[i][j][0] * r0);
        dst[(long)(rb + 1) * ldc + col] = f2bf(acc[i][j][1] * r1);
        dst[(long)(rb + 2) * ldc + col] = f2bf(acc[i][j][2] * r2);
        dst[(long)(rb + 3) * ldc + col] = f2bf(acc[i][j][3] * r3);
      }
    }
  }
}

// ---------------- residual + split-K combine + LayerNorm (bf16 attn inputs) ----------------
__global__ __launch_bounds__(256) void residual_ln(
    const unsigned short* __restrict__ attn, const unsigned short* __restrict__ attn2,
    const float* __restrict__ x,
    const float* __restrict__ gamma, const float* __restrict__ beta,
    float* __restrict__ out) {
  __shared__ float rs[4], rs2[4];
  const long row = blockIdx.x;
  const int t = threadIdx.x;
  const int lane = t & 63, wave = t >> 6;
  const ushort4 a  = ((const ushort4*)(attn + row * E_))[t];
  const float4 xv = ((const float4*)(x + row * E_))[t];
  ushort4 b2 = make_ushort4(0, 0, 0, 0);
  if ((row & (S_ - 1)) >= 1024) b2 = ((const ushort4*)(attn2 + row * E_))[t];
  const float y0 = bf2f(a.x) + bf2f(b2.x) + xv.x;
  const float y1 = bf2f(a.y) + bf2f(b2.y) + xv.y;
  const float y2 = bf2f(a.z) + bf2f(b2.z) + xv.z;
  const float y3 = bf2f(a.w) + bf2f(b2.w) + xv.w;
  float s  = y0 + y1 + y2 + y3;
  float s2 = y0 * y0 + y1 * y1 + y2 * y2 + y3 * y3;
#pragma unroll
  for (int o = 32; o; o >>= 1) { s += __shfl_xor(s, o); s2 += __shfl_xor(s2, o); }
  if (lane == 0) { rs[wave] = s; rs2[wave] = s2; }
  __syncthreads();
  s  = rs[0] + rs[1] + rs[2] + rs[3];
  s2 = rs2[0] + rs2[1] + rs2[2] + rs2[3];
  const float mu  = s * (1.0f / E_);
  const float var = s2 * (1.0f / E_) - mu * mu;
  const float inv = rsqrtf(var + 1e-5f);
  const float4 g  = ((const float4*)gamma)[t];
  const float4 be = ((const float4*)beta)[t];
  float4 o;
  o.x = (y0 - mu) * inv * g.x + be.x;
  o.y = (y1 - mu) * inv * g.y + be.y;
  o.z = (y2 - mu) * inv * g.z + be.z;
  o.w = (y3 - mu) * inv * g.w + be.w;
  ((float4*)(out + row * E_))[t] = o;
}

extern "C" void kernel_launch(void* const* d_in, const int* in_sizes, int n_in,
                              void* d_out, int out_size, void* d_ws, size_t ws_size,
                              hipStream_t stream) {
  const float* x  = (const float*)d_in[0];
  // d_in[1] = causal mask (bool) — structurally known, not read
  const float* Wq = (const float*)d_in[2];
  const float* bq = (const float*)d_in[3];
  const float* Wk = (const float*)d_in[4];
  const float* bk = (const float*)d_in[5];
  const float* Wv = (const float*)d_in[6];
  const float* bv = (const float*)d_in[7];
  const float* gamma = (const float*)d_in[8];
  const float* beta  = (const float*)d_in[9];
  float* out = (float*)d_out;

  char* ws = (char*)d_ws;
  size_t off = 0;
  auto alloc = [&](size_t bytes) { char* p = ws + off; off += (bytes + 255) & ~(size_t)255; return p; };
  unsigned short* xb    = (unsigned short*)alloc((size_t)BS_ * E_ * 2);        // 16 MB
  unsigned short* Wqkvb = (unsigned short*)alloc((size_t)3 * E_ * E_ * 2);     // 6 MB
  float*          bqkv  = (float*)alloc((size_t)3 * E_ * 4);
  unsigned short* Cqkv  = (unsigned short*)alloc((size_t)BS_ * 2 * E_ * 2);    // 32 MB (Q|K, ld 2048)
  unsigned short* Vt    = (unsigned short*)alloc((size_t)BS_ * E_ * 2);        // 16 MB
  unsigned short* Sc    = (unsigned short*)alloc((size_t)B_ * S_ * S_ * 2);    // 32 MB bf16 P_unnorm
  float*          lrow  = (float*)alloc((size_t)BS_ * 4);                      // 32 KB rowsums
  unsigned short* attn  = (unsigned short*)Cqkv;            // bf16, 16 MB (Q/K dead after scores)
  unsigned short* attn2 = (unsigned short*)Cqkv + (size_t)BS_ * E_;  // bf16, 16 MB

  // 1) all converts + zero rowsums, one launch
  const int nprep = BS_ * E_ / 4 + 3 * E_ * E_ / 4 + 3 * E_ + BS_;
  prep_all<<<dim3((nprep + 255) / 256), 256, 0, stream>>>(x, Wq, Wk, Wv, bq, bk, bv,
                                                          xb, Wqkvb, bqkv, lrow);

  // 2) fused QKV projection; Q|K -> Cqkv (ld 2048), V -> Vt transposed (LDS-coalesced)
  dim3 g1(3 * E_ / 128, BS_ / 128, 1);
  gemm_bt<0><<<g1, 256, 0, stream>>>(xb, Wqkvb, nullptr, Cqkv, Vt, bqkv,
                                     E_, E_, E_, 2 * E_, 0, 0, 0, 1.f);

  // 3) scores: P_unnorm = exp(Q·K^T/32) masked -> bf16; rowsums -> lrow (atomic)
  gemm_bt<1><<<dim3(544), 256, 0, stream>>>(Cqkv, Cqkv + E_, lrow, Sc, nullptr, nullptr,
                                            E_, 2 * E_, 2 * E_, S_,
                                            (long)S_ * 2 * E_, (long)S_ * 2 * E_, (long)S_ * S_,
                                            0.03125f);

  // 4) attn = (P_unnorm · V) / l, bf16 out; split-K balanced: 8 x 24 x 4 = 768 blocks
  dim3 g3(E_ / 128, 24, B_);
  gemm_bt<2><<<g3, 256, 0, stream>>>(Sc, Vt, lrow, attn, attn2, nullptr,
                                     S_, S_, S_, E_,
                                     (long)S_ * S_, (long)S_ * E_, (long)S_ * E_, 1.f);

  // 5) out = LayerNorm(attn [+ attn2] + x) * gamma + beta
  residual_ln<<<dim3(BS_), 256, 0, stream>>>(attn, attn2, x, gamma, beta, out);
}

// Round 9
// 267.706 us; speedup vs baseline: 1.1480x; 1.0217x over previous
//
#include <hip/hip_runtime.h>
#include <hip/hip_bf16.h>
#include <stdint.h>

#define B_ 4
#define S_ 2048
#define E_ 1024
#define BS_ (B_*S_)

using bf16x8 = __attribute__((ext_vector_type(8))) __bf16;
using f32x4  = __attribute__((ext_vector_type(4))) float;

// PV split-K schedule: 24 chunks/(n,b), descending K so long chunks dispatch first.
// mt 0..7: one chunk [0, 128(mt+1)); mt 8..15: chunk0 [0,1024) -> attn, chunk1 [1024, 128(mt+1)) -> attn2
__constant__ int pv_mt[24] = {7,8,9,10,11,12,13,14,15,15,14,6,13,5,12,4,11,3,10,2,9,1,8,0};
__constant__ int pv_ck[24] = {0,0,0,0,0,0,0,0,0, 1, 1,0, 1,0, 1,0, 1,0, 1,0, 1,0, 1,0};

__device__ __forceinline__ unsigned short f2bf(float f) {
  unsigned int u = __float_as_uint(f);
  u += 0x7fffu + ((u >> 16) & 1u);          // round-to-nearest-even
  return (unsigned short)(u >> 16);
}
__device__ __forceinline__ float bf2f(unsigned short h) {
  return __uint_as_float(((unsigned int)h) << 16);
}

// async global->LDS, 16B per lane; LDS dest = wave-uniform base + lane*16
__device__ __forceinline__ void gld16(const unsigned short* g, unsigned short* l) {
  __builtin_amdgcn_global_load_lds((__attribute__((address_space(1))) void*)(void*)g,
                                   (__attribute__((address_space(3))) void*)l, 16, 0, 0);
}

// ---------------- prep: x->bf16, W->bf16 concat, bias concat, zero l ----------------
__global__ __launch_bounds__(256) void prep_all(
    const float* __restrict__ x,
    const float* __restrict__ Wq, const float* __restrict__ Wk, const float* __restrict__ Wv,
    const float* __restrict__ bq, const float* __restrict__ bk, const float* __restrict__ bv,
    unsigned short* __restrict__ xb, unsigned short* __restrict__ Wb, float* __restrict__ bb,
    float* __restrict__ lz) {
  const int i = blockIdx.x * 256 + threadIdx.x;
  const int nx4 = BS_ * E_ / 4, nw4 = E_ * E_ / 4;
  if (i < nx4) {
    const float4 v = ((const float4*)x)[i];
    ushort4 o;
    o.x = f2bf(v.x); o.y = f2bf(v.y); o.z = f2bf(v.z); o.w = f2bf(v.w);
    ((ushort4*)xb)[i] = o;
  } else if (i < nx4 + 3 * nw4) {
    const int j = i - nx4;
    const int m = j / nw4, jj = j - m * nw4;
    const float* src = (m == 0) ? Wq : (m == 1) ? Wk : Wv;
    const float4 v = ((const float4*)src)[jj];
    ushort4 o;
    o.x = f2bf(v.x); o.y = f2bf(v.y); o.z = f2bf(v.z); o.w = f2bf(v.w);
    ((ushort4*)Wb)[j] = o;
  } else {
    const int j = i - nx4 - 3 * nw4;
    if (j < 3 * E_) bb[j] = (j < E_) ? bq[j] : (j < 2 * E_) ? bk[j - E_] : bv[j - 2 * E_];
    else { const int k = j - 3 * E_; if (k < BS_) lz[k] = 0.f; }
  }
}

// ---------------- shared BT-GEMM body (m97 structure) ----------------
// C[m][n] = sum_k A[m][k]*B[n][k]
// EPI 0 (QKV):   +bias; cols <2048 -> bf16 Cqkv; cols >=2048 -> V transposed to Vt via LDS scratch
// EPI 1 (scores):mask+exp(s*scale) -> bf16 P_unnorm; per-row atomicAdd rowsum into Cf(=l)
// EPI 2 (PV):    divide by l (Cf), write bf16; split-K: chunk0 -> Cb(attn), chunk1 -> VtOut(attn2)
template<int EPI>
__device__ __forceinline__ void gemm_body(
    const unsigned short* __restrict__ A, const unsigned short* __restrict__ Bm,
    float* __restrict__ Cf,
    unsigned short* __restrict__ Cb, unsigned short* __restrict__ VtOut,
    const float* __restrict__ bias,
    int K, int lda, int ldb, int ldc,
    long sA, long sB, long sC, float scale)
{
  constexpr int BM = 128, BN = 128, BK = 64;
  __shared__ __align__(16) unsigned short As[BM * BK];
  __shared__ __align__(16) unsigned short Bs[BN * BK];

  int mt, nt, ck = 0, bz;
  if (EPI == 1) {
    // sigma: XCD c = id%8 processes contiguous locality-ordered segment [68c, 68c+68)
    const int sig = (blockIdx.x & 7) * 68 + (blockIdx.x >> 3);
    bz = sig / 136;
    const int rem = sig - bz * 136;
    const int M = (rem >= 78) ? 3 : (rem >= 36) ? 2 : (rem >= 10) ? 1 : 0;
    const int cumM = (M == 3) ? 78 : (M == 2) ? 36 : (M == 1) ? 10 : 0;
    const int inner = rem - cumM;
    if (inner < 16 * M) {               // full 4x4 super (N < M)
      const int N = inner >> 4, t2 = inner & 15;
      mt = 4 * M + (t2 >> 2); nt = 4 * N + (t2 & 3);
    } else {                            // diagonal tri super (N == M), 10 tiles
      const int t2 = inner - 16 * M;
      const int ml = (t2 >= 6) ? 3 : (t2 >= 3) ? 2 : (t2 >= 1) ? 1 : 0;
      const int nl = t2 - (ml * (ml + 1)) / 2;
      mt = 4 * M + ml; nt = 4 * M + nl;
    }
  } else if (EPI == 2) {
    mt = pv_mt[blockIdx.y]; ck = pv_ck[blockIdx.y]; nt = blockIdx.x; bz = blockIdx.z;
  } else {
    mt = blockIdx.y; nt = blockIdx.x; bz = blockIdx.z;
  }
  A  += sA * bz;
  Bm += sB * bz;
  const int m0 = mt * BM, n0 = nt * BN;
  const int k0s  = (EPI == 2 && ck) ? 1024 : 0;
  const int kend = (EPI == 2) ? (ck ? m0 + BM : min(1024, m0 + BM)) : K;

  const int t = threadIdx.x;
  const int lane = t & 63, wave = t >> 6;
  const int wr = wave >> 1, wc = wave & 1;
  const int q = lane >> 4, r = lane & 15;

  // staging: wave w handles rows [w*32, w*32+32), 4 instructions of 8 rows each
  const int srow   = lane >> 3;                 // 0..7 within an 8-row segment
  const int schunk = (lane & 7) ^ srow;         // global 16B chunk to fetch
  const long ga0 = (long)(m0 + wave * 32 + srow) * lda + schunk * 8;
  const long gb0 = (long)(n0 + wave * 32 + srow) * ldb + schunk * 8;

  f32x4 acc[4][4] = {};

  for (int k0 = k0s; k0 < kend; k0 += BK) {
#pragma unroll
    for (int s = 0; s < 4; ++s) {
      gld16(A  + ga0 + (long)s * 8 * lda + k0, &As[(wave * 32 + s * 8) * 64]);
      gld16(Bm + gb0 + (long)s * 8 * ldb + k0, &Bs[(wave * 32 + s * 8) * 64]);
    }
    __syncthreads();                            // vmcnt(0) drain + barrier: tiles ready
#pragma unroll
    for (int kk = 0; kk < BK; kk += 32) {
      bf16x8 af[4], bfr[4];
      const int cq = (kk >> 3) + q;             // 16B chunk for this quad
#pragma unroll
      for (int i = 0; i < 4; ++i) {
        const int row = wr * 64 + i * 16 + r;
        af[i] = *(const bf16x8*)&As[(row * 8 + (cq ^ (r & 7))) * 8];
      }
#pragma unroll
      for (int j = 0; j < 4; ++j) {
        const int row = wc * 64 + j * 16 + r;
        bfr[j] = *(const bf16x8*)&Bs[(row * 8 + (cq ^ (r & 7))) * 8];
      }
#pragma unroll
      for (int i = 0; i < 4; ++i)
#pragma unroll
        for (int j = 0; j < 4; ++j)
          acc[i][j] = __builtin_amdgcn_mfma_f32_16x16x32_bf16(af[i], bfr[j], acc[i][j], 0, 0, 0);
    }
    __syncthreads();                            // all reads done before next staging
  }

  if (EPI == 0) {
    if (n0 < 2 * E_) {                          // Q|K -> Cqkv (ld 2048)
#pragma unroll
    for (int i = 0; i < 4; ++i)
#pragma unroll
      for (int j = 0; j < 4; ++j) {
        const int col = n0 + wc * 64 + j * 16 + r;
        const float bia = bias[col];
#pragma unroll
        for (int e = 0; e < 4; ++e) {
          const int rowg = m0 + wr * 64 + i * 16 + q * 4 + e;
          Cb[(long)rowg * ldc + col] = f2bf(acc[i][j][e] + bia);
        }
      }
    } else {
      // V -> Vt[b][e][s]: per-wave LDS scratch transpose, then coalesced 16B stores.
      unsigned short* scr = As + wave * 2048;   // 4 KB private scratch (K-loop done)
      const int bb = m0 >> 11;
      const int sbase = (m0 & (S_ - 1)) + wr * 64;
#pragma unroll
      for (int j = 0; j < 4; ++j) {
        const int e_base = n0 - 2 * E_ + wc * 64 + j * 16;
        const float bj = bias[n0 + wc * 64 + j * 16 + r];
#pragma unroll
        for (int i = 0; i < 4; ++i) {
          const int c = 2 * i + (q >> 1);       // s-chunk (8 elems)
          const int slot = c ^ (r & 7);
          ushort4 o;
          o.x = f2bf(acc[i][j][0] + bj);
          o.y = f2bf(acc[i][j][1] + bj);
          o.z = f2bf(acc[i][j][2] + bj);
          o.w = f2bf(acc[i][j][3] + bj);
          *(ushort4*)&scr[r * 72 + slot * 8 + (q & 1) * 4] = o;
        }
#pragma unroll
        for (int it = 0; it < 2; ++it) {
          const int er = it * 8 + (lane >> 3);
          const int w = lane & 7;
          const bf16x8 vv = *(const bf16x8*)&scr[er * 72 + w * 8];
          const int so = (w ^ (er & 7)) * 8;
          *(bf16x8*)&VtOut[((long)bb * E_ + e_base + er) * S_ + sbase + so] = vv;
        }
      }
    }
  } else if (EPI == 1) {
    // mask + exp + write P_unnorm (bf16) + per-row atomic rowsum
    Cb += sC * bz;
    float* lv = Cf + (long)bz * S_;
#pragma unroll
    for (int i = 0; i < 4; ++i) {
      float rs[4] = {0.f, 0.f, 0.f, 0.f};
#pragma unroll
      for (int j = 0; j < 4; ++j) {
        const int col = n0 + wc * 64 + j * 16 + r;
#pragma unroll
        for (int e = 0; e < 4; ++e) {
          const int rowg = m0 + wr * 64 + i * 16 + q * 4 + e;
          float p = 0.f;
          if (col <= rowg) p = __expf(fminf(acc[i][j][e] * scale, 60.f));
          Cb[(long)rowg * ldc + col] = f2bf(p);
          rs[e] += p;
        }
      }
#pragma unroll
      for (int e = 0; e < 4; ++e) {
        float s = rs[e];
        s += __shfl_xor(s, 1); s += __shfl_xor(s, 2);
        s += __shfl_xor(s, 4); s += __shfl_xor(s, 8);   // reduce across the 16 r-lanes
        if (r == 0) atomicAdd(&lv[m0 + wr * 64 + i * 16 + q * 4 + e], s);
      }
    }
  } else {
    // PV: normalize by rowsum, write bf16
    const float* lv = Cf + (long)bz * S_;
    unsigned short* dst = (ck ? VtOut : Cb) + sC * bz;
#pragma unroll
    for (int i = 0; i < 4; ++i) {
      const int rb = m0 + wr * 64 + i * 16 + q * 4;
      const float4 l4 = *(const float4*)&lv[rb];
      const float r0 = 1.f / l4.x, r1 = 1.f / l4.y, r2 = 1.f / l4.z, r3 = 1.f / l4.w;
#pragma unroll
      for (int j = 0; j < 4; ++j) {
        const int col = n0 + wc * 64 + j * 16 + r;
        dst[(long)(rb + 0) * ldc + col] = f2bf(acc[i][j][0] * r0);
        dst[(long)(rb + 1) * ldc + col] = f2bf(acc[i][j][1] * r1);
        dst[(long)(rb + 2) * ldc + col] = f2bf(acc[i][j][2] * r2);
        dst[(long)(rb + 3) * ldc + col] = f2bf(acc[i][j][3] * r3);
      }
    }
  }
}

// distinct names per stage so rocprof top-k shows per-stage durations
__global__ __launch_bounds__(256, 4) void gemm_qkv(
    const unsigned short* A, const unsigned short* Bm, float* Cf,
    unsigned short* Cb, unsigned short* VtOut, const float* bias,
    int K, int lda, int ldb, int ldc, long sA, long sB, long sC, float scale) {
  gemm_body<0>(A, Bm, Cf, Cb, VtOut, bias, K, lda, ldb, ldc, sA, sB, sC, scale);
}
__global__ __launch_bounds__(256, 4) void gemm_sc(
    const unsigned short* A, const unsigned short* Bm, float* Cf,
    unsigned short* Cb, unsigned short* VtOut, const float* bias,
    int K, int lda, int ldb, int ldc, long sA, long sB, long sC, float scale) {
  gemm_body<1>(A, Bm, Cf, Cb, VtOut, bias, K, lda, ldb, ldc, sA, sB, sC, scale);
}
__global__ __launch_bounds__(256, 4) void gemm_pv(
    const unsigned short* A, const unsigned short* Bm, float* Cf,
    unsigned short* Cb, unsigned short* VtOut, const float* bias,
    int K, int lda, int ldb, int ldc, long sA, long sB, long sC, float scale) {
  gemm_body<2>(A, Bm, Cf, Cb, VtOut, bias, K, lda, ldb, ldc, sA, sB, sC, scale);
}

// ---------------- residual (bf16 x) + split-K combine + LayerNorm ----------------
__global__ __launch_bounds__(256) void residual_ln(
    const unsigned short* __restrict__ attn, const unsigned short* __restrict__ attn2,
    const unsigned short* __restrict__ xb,
    const float* __restrict__ gamma, const float* __restrict__ beta,
    float* __restrict__ out) {
  __shared__ float rs[4], rs2[4];
  const long row = blockIdx.x;
  const int t = threadIdx.x;
  const int lane = t & 63, wave = t >> 6;
  const ushort4 a  = ((const ushort4*)(attn + row * E_))[t];
  const ushort4 xv = ((const ushort4*)(xb + row * E_))[t];
  ushort4 b2 = make_ushort4(0, 0, 0, 0);
  if ((row & (S_ - 1)) >= 1024) b2 = ((const ushort4*)(attn2 + row * E_))[t];
  const float y0 = bf2f(a.x) + bf2f(b2.x) + bf2f(xv.x);
  const float y1 = bf2f(a.y) + bf2f(b2.y) + bf2f(xv.y);
  const float y2 = bf2f(a.z) + bf2f(b2.z) + bf2f(xv.z);
  const float y3 = bf2f(a.w) + bf2f(b2.w) + bf2f(xv.w);
  float s  = y0 + y1 + y2 + y3;
  float s2 = y0 * y0 + y1 * y1 + y2 * y2 + y3 * y3;
#pragma unroll
  for (int o = 32; o; o >>= 1) { s += __shfl_xor(s, o); s2 += __shfl_xor(s2, o); }
  if (lane == 0) { rs[wave] = s; rs2[wave] = s2; }
  __syncthreads();
  s  = rs[0] + rs[1] + rs[2] + rs[3];
  s2 = rs2[0] + rs2[1] + rs2[2] + rs2[3];
  const float mu  = s * (1.0f / E_);
  const float var = s2 * (1.0f / E_) - mu * mu;
  const float inv = rsqrtf(var + 1e-5f);
  const float4 g  = ((const float4*)gamma)[t];
  const float4 be = ((const float4*)beta)[t];
  float4 o;
  o.x = (y0 - mu) * inv * g.x + be.x;
  o.y = (y1 - mu) * inv * g.y + be.y;
  o.z = (y2 - mu) * inv * g.z + be.z;
  o.w = (y3 - mu) * inv * g.w + be.w;
  ((float4*)(out + row * E_))[t] = o;
}

extern "C" void kernel_launch(void* const* d_in, const int* in_sizes, int n_in,
                              void* d_out, int out_size, void* d_ws, size_t ws_size,
                              hipStream_t stream) {
  const float* x  = (const float*)d_in[0];
  // d_in[1] = causal mask (bool) — structurally known, not read
  const float* Wq = (const float*)d_in[2];
  const float* bq = (const float*)d_in[3];
  const float* Wk = (const float*)d_in[4];
  const float* bk = (const float*)d_in[5];
  const float* Wv = (const float*)d_in[6];
  const float* bv = (const float*)d_in[7];
  const float* gamma = (const float*)d_in[8];
  const float* beta  = (const float*)d_in[9];
  float* out = (float*)d_out;

  char* ws = (char*)d_ws;
  size_t off = 0;
  auto alloc = [&](size_t bytes) { char* p = ws + off; off += (bytes + 255) & ~(size_t)255; return p; };
  unsigned short* xb    = (unsigned short*)alloc((size_t)BS_ * E_ * 2);        // 16 MB
  unsigned short* Wqkvb = (unsigned short*)alloc((size_t)3 * E_ * E_ * 2);     // 6 MB
  float*          bqkv  = (float*)alloc((size_t)3 * E_ * 4);
  unsigned short* Cqkv  = (unsigned short*)alloc((size_t)BS_ * 2 * E_ * 2);    // 32 MB (Q|K, ld 2048)
  unsigned short* Vt    = (unsigned short*)alloc((size_t)BS_ * E_ * 2);        // 16 MB
  unsigned short* Sc    = (unsigned short*)alloc((size_t)B_ * S_ * S_ * 2);    // 32 MB bf16 P_unnorm
  float*          lrow  = (float*)alloc((size_t)BS_ * 4);                      // 32 KB rowsums
  unsigned short* attn  = (unsigned short*)Cqkv;            // bf16, 16 MB (Q/K dead after scores)
  unsigned short* attn2 = (unsigned short*)Cqkv + (size_t)BS_ * E_;  // bf16, 16 MB

  // 1) all converts + zero rowsums, one launch
  const int nprep = BS_ * E_ / 4 + 3 * E_ * E_ / 4 + 3 * E_ + BS_;
  prep_all<<<dim3((nprep + 255) / 256), 256, 0, stream>>>(x, Wq, Wk, Wv, bq, bk, bv,
                                                          xb, Wqkvb, bqkv, lrow);

  // 2) fused QKV projection; Q|K -> Cqkv (ld 2048), V -> Vt transposed (LDS-coalesced)
  dim3 g1(3 * E_ / 128, BS_ / 128, 1);
  gemm_qkv<<<g1, 256, 0, stream>>>(xb, Wqkvb, nullptr, Cqkv, Vt, bqkv,
                                   E_, E_, E_, 2 * E_, 0, 0, 0, 1.f);

  // 3) scores: P_unnorm = exp(Q·K^T/32) masked -> bf16; rowsums -> lrow (atomic)
  gemm_sc<<<dim3(544), 256, 0, stream>>>(Cqkv, Cqkv + E_, lrow, Sc, nullptr, nullptr,
                                         E_, 2 * E_, 2 * E_, S_,
                                         (long)S_ * 2 * E_, (long)S_ * 2 * E_, (long)S_ * S_,
                                         0.03125f);

  // 4) attn = (P_unnorm · V) / l, bf16 out; split-K balanced: 8 x 24 x 4 = 768 blocks
  dim3 g3(E_ / 128, 24, B_);
  gemm_pv<<<g3, 256, 0, stream>>>(Sc, Vt, lrow, attn, attn2, nullptr,
                                  S_, S_, S_, E_,
                                  (long)S_ * S_, (long)S_ * E_, (long)S_ * E_, 1.f);

  // 5) out = LayerNorm(attn [+ attn2] + xb) * gamma + beta
  residual_ln<<<dim3(BS_), 256, 0, stream>>>(attn, attn2, xb, gamma, beta, out);
}